// Round 3
// baseline (1591.152 us; speedup 1.0000x reference)
//
#include <hip/hip_runtime.h>
#include <hip/hip_bf16.h>
#include <math.h>

#define NB   512        // queries
#define ND   64         // dim
#define NC   1000000    // candidates
#define TOPK 100
#define SAMP 8192       // sampled candidates for threshold
#define SAMP_R 8        // take 8th largest of sample as threshold
#define SSTR 122        // 8191*122 = 999302 < 1e6
#define CAP  4096       // survivor buffer per query

// f32 score, sequential FMA over d — must be the SAME everywhere so bits match
// the hypothesized np reference (BLAS-style k-ascending single-accumulator FMA).
__device__ __forceinline__ float score_f32(const float* __restrict__ c,
                                           const float* __restrict__ q)
{
    float s = 0.f;
#pragma unroll
    for (int d = 0; d < ND; ++d) s = fmaf(c[d], q[d], s);
    return s;
}

// ---------------- K0: per-query threshold from sampled candidates ----------
__global__ __launch_bounds__(256) void k0_sample(const float* __restrict__ qs,
                                                 const float* __restrict__ cs,
                                                 float* __restrict__ T)
{
    __shared__ float ls[SAMP];
    __shared__ float red[256];
    __shared__ int   redi[256];
    __shared__ float lq[ND];
    const int qi = blockIdx.x;
    const int tid = threadIdx.x;
    if (tid < ND) lq[tid] = qs[qi * ND + tid];
    __syncthreads();
    for (int j = tid; j < SAMP; j += 256)
        ls[j] = score_f32(cs + (size_t)(j * SSTR) * ND, lq);
    __syncthreads();
    float thr = 0.f;
    for (int it = 0; it < SAMP_R; ++it) {
        float m = -INFINITY; int mi = 0;
        for (int j = tid; j < SAMP; j += 256)
            if (ls[j] > m) { m = ls[j]; mi = j; }
        red[tid] = m; redi[tid] = mi;
        __syncthreads();
        for (int off = 128; off > 0; off >>= 1) {
            if (tid < off && red[tid + off] > red[tid]) {
                red[tid] = red[tid + off]; redi[tid] = redi[tid + off];
            }
            __syncthreads();
        }
        thr = red[0];
        if (tid == 0) ls[redi[0]] = -INFINITY;
        __syncthreads();
    }
    if (tid == 0) T[qi] = thr;
}

// ---------------- K1: full fp32 scoring pass, collect survivors ------------
__global__ __launch_bounds__(256) void k1_collect(const float* __restrict__ qs,
                                                  const float* __restrict__ cs,
                                                  const float* __restrict__ T,
                                                  unsigned int* __restrict__ cnt,
                                                  int* __restrict__ buf)
{
    const int tid0 = blockIdx.x * 256 + threadIdx.x;
    const int stride = gridDim.x * 256;
    for (int n = tid0; n < NC; n += stride) {
        float cv[ND];
        const float* cp = cs + (size_t)n * ND;
#pragma unroll
        for (int d = 0; d < ND; ++d) cv[d] = cp[d];
        for (int q = 0; q < NB; ++q) {
            float s = 0.f;
#pragma unroll
            for (int d = 0; d < ND; ++d) s = fmaf(cv[d], qs[q * ND + d], s);
            if (s >= T[q]) {
                unsigned int p = atomicAdd(&cnt[q], 1u);
                if (p < CAP) buf[(size_t)q * CAP + p] = n;
            }
        }
    }
}

// ---------------- K2: f32 rescore survivors + exact top-K (f32 order) ------
__device__ __forceinline__ bool prec(float av, int ai, float bv, int bi)
{
    // strict "a precedes b": larger f32 score first, ties -> lower index
    return (av > bv) || (av == bv && ai < bi);
}

__device__ void bitonic_desc(float* v, int* ix, int n, int tid)
{
    for (int k = 2; k <= n; k <<= 1) {
        for (int j = k >> 1; j > 0; j >>= 1) {
            for (int i = tid; i < n; i += 256) {
                int p = i ^ j;
                if (p > i) {
                    bool swap_;
                    if ((i & k) == 0) swap_ = prec(v[p], ix[p], v[i], ix[i]);
                    else              swap_ = prec(v[i], ix[i], v[p], ix[p]);
                    if (swap_) {
                        float tv_ = v[i]; v[i] = v[p]; v[p] = tv_;
                        int   ti_ = ix[i]; ix[i] = ix[p]; ix[p] = ti_;
                    }
                }
            }
            __syncthreads();
        }
    }
}

__global__ __launch_bounds__(256) void k2_final(const float* __restrict__ qs,
                                                const float* __restrict__ cs,
                                                const unsigned int* __restrict__ cnt,
                                                const int* __restrict__ buf,
                                                float* __restrict__ out)
{
    __shared__ float sv[CAP];
    __shared__ int   si[CAP];
    __shared__ float tv[128];
    __shared__ int   ti[128];
    __shared__ float lq[ND];
    const int qi = blockIdx.x;
    const int tid = threadIdx.x;
    if (tid < ND) lq[tid] = qs[qi * ND + tid];
    __syncthreads();
    const unsigned int c = cnt[qi];
    const bool fix = (c < TOPK) || (c > CAP);
    if (!fix) {
        const int m = (int)c;
        for (int i = tid; i < CAP; i += 256) {
            if (i < m) {
                const int n = buf[(size_t)qi * CAP + i];
                sv[i] = score_f32(cs + (size_t)n * ND, lq);
                si[i] = n;
            } else { sv[i] = -INFINITY; si[i] = 0x7fffffff; }
        }
        __syncthreads();
        bitonic_desc(sv, si, CAP, tid);
        for (int j = tid; j < TOPK; j += 256) {
            out[qi * TOPK + j] = sv[j];                       // values (f32, ref bits)
            out[NB * TOPK + qi * TOPK + j] = (float)si[j];    // indices as f32
        }
    } else {
        // exact fallback (rare): chunked full scan with carried top-128, same f32 order
        for (int i = tid; i < 128; i += 256) { tv[i] = -INFINITY; ti[i] = 0x7fffffff; }
        __syncthreads();
        const int CH = CAP - 128;
        for (int base = 0; base < NC; base += CH) {
            for (int i = tid; i < CAP; i += 256) {
                if (i < 128) { sv[i] = tv[i]; si[i] = ti[i]; }
                else {
                    const int n = base + (i - 128);
                    if (n < NC) {
                        sv[i] = score_f32(cs + (size_t)n * ND, lq);
                        si[i] = n;
                    } else { sv[i] = -INFINITY; si[i] = 0x7fffffff; }
                }
            }
            __syncthreads();
            bitonic_desc(sv, si, CAP, tid);
            for (int i = tid; i < 128; i += 256) { tv[i] = sv[i]; ti[i] = si[i]; }
            __syncthreads();
        }
        for (int j = tid; j < TOPK; j += 256) {
            out[qi * TOPK + j] = tv[j];
            out[NB * TOPK + qi * TOPK + j] = (float)ti[j];
        }
    }
}

extern "C" void kernel_launch(void* const* d_in, const int* in_sizes, int n_in,
                              void* d_out, int out_size, void* d_ws, size_t ws_size,
                              hipStream_t stream)
{
    const float* qs = (const float*)d_in[0];
    const float* cs = (const float*)d_in[1];
    float*        T   = (float*)d_ws;
    unsigned int* cnt = (unsigned int*)((char*)d_ws + 2048);
    int*          buf = (int*)((char*)d_ws + 4096);
    float* out = (float*)d_out;

    hipMemsetAsync(cnt, 0, NB * sizeof(unsigned int), stream);
    k0_sample<<<NB, 256, 0, stream>>>(qs, cs, T);
    k1_collect<<<2048, 256, 0, stream>>>(qs, cs, T, cnt, buf);
    k2_final<<<NB, 256, 0, stream>>>(qs, cs, cnt, buf, out);
}

// Round 4
// 926.341 us; speedup vs baseline: 1.7177x; 1.7177x over previous
//
#include <hip/hip_runtime.h>
#include <hip/hip_bf16.h>
#include <math.h>

#define NB   512        // queries
#define ND   64         // dim
#define NC   1000000    // candidates
#define TOPK 100
#define SAMP 8192       // sampled candidates for threshold
#define SAMP_R 8        // take 8th largest of sample as threshold
#define SSTR 122        // 8191*122 = 999302 < 1e6
#define CAP  4096       // survivor buffer per query
#define NTILES 31250    // NC / 32 (exact)
#define MARGIN 0.5f     // bf16-scoring safety margin (error ~0.03 std, 0.2 max)

typedef __attribute__((ext_vector_type(8)))  short bf16x8;
typedef __attribute__((ext_vector_type(16))) float f32x16;

// f32 score, sequential FMA over d — bit-matches the np reference contraction.
__device__ __forceinline__ float score_f32(const float* __restrict__ c,
                                           const float* __restrict__ q)
{
    float s = 0.f;
#pragma unroll
    for (int d = 0; d < ND; ++d) s = fmaf(c[d], q[d], s);
    return s;
}

__device__ __forceinline__ unsigned int pack_bf16(float lo, float hi)
{
    unsigned int ul = __float_as_uint(lo), uh = __float_as_uint(hi);
    ul = (ul + 0x7fffu + ((ul >> 16) & 1u)) >> 16;   // RNE f32->bf16
    uh = (uh + 0x7fffu + ((uh >> 16) & 1u)) >> 16;
    return (uh << 16) | (ul & 0xffffu);
}

// ---------------- K0: per-query threshold from sampled candidates ----------
__global__ __launch_bounds__(256) void k0_sample(const float* __restrict__ qs,
                                                 const float* __restrict__ cs,
                                                 float* __restrict__ T)
{
    __shared__ float ls[SAMP];
    __shared__ float red[256];
    __shared__ int   redi[256];
    __shared__ float lq[ND];
    const int qi = blockIdx.x;
    const int tid = threadIdx.x;
    if (tid < ND) lq[tid] = qs[qi * ND + tid];
    __syncthreads();
    for (int j = tid; j < SAMP; j += 256)
        ls[j] = score_f32(cs + (size_t)(j * SSTR) * ND, lq);
    __syncthreads();
    float thr = 0.f;
    for (int it = 0; it < SAMP_R; ++it) {
        float m = -INFINITY; int mi = 0;
        for (int j = tid; j < SAMP; j += 256)
            if (ls[j] > m) { m = ls[j]; mi = j; }
        red[tid] = m; redi[tid] = mi;
        __syncthreads();
        for (int off = 128; off > 0; off >>= 1) {
            if (tid < off && red[tid + off] > red[tid]) {
                red[tid] = red[tid + off]; redi[tid] = redi[tid + off];
            }
            __syncthreads();
        }
        thr = red[0];
        if (tid == 0) ls[redi[0]] = -INFINITY;
        __syncthreads();
    }
    if (tid == 0) T[qi] = thr;
}

// ---------------- K1: bf16 MFMA pruning pass ------------------------------
// Each block: 8 candidate tiles of 32 rows (2 per wave), all 512 queries.
// Q converted once to fragment-major bf16 in LDS; A-frags converted from f32
// in-register and held in VGPRs across all 16 query tiles.
__global__ __launch_bounds__(256) void k1_mfma(const float* __restrict__ qs,
                                               const float* __restrict__ cs,
                                               const float* __restrict__ T,
                                               unsigned int* __restrict__ cnt,
                                               int* __restrict__ buf)
{
    __shared__ unsigned int qlds[16384];   // 64 KB: (qt,k0,lane) fragment-major bf16 Q
    __shared__ float tlds[NB];             // T - margin
    const int tid = threadIdx.x;

    // stage Q: 512 rows x 8 chunks of 8 elems; coalesced f32 reads, RNE pack
    for (int g = tid; g < 4096; g += 256) {
        const int qrow = g >> 3, c = g & 7;
        const float* src = qs + qrow * ND + c * 8;
        const float4 f0 = *(const float4*)src;
        const float4 f1 = *(const float4*)(src + 4);
        const int chunk = (((qrow >> 5) * 4 + (c >> 1)) * 64) + (c & 1) * 32 + (qrow & 31);
        qlds[chunk * 4 + 0] = pack_bf16(f0.x, f0.y);
        qlds[chunk * 4 + 1] = pack_bf16(f0.z, f0.w);
        qlds[chunk * 4 + 2] = pack_bf16(f1.x, f1.y);
        qlds[chunk * 4 + 3] = pack_bf16(f1.z, f1.w);
    }
    for (int i = tid; i < NB; i += 256) tlds[i] = T[i] - MARGIN;
    __syncthreads();

    const int wave = tid >> 6, lane = tid & 63;
    const int arow = lane & 31, khalf = lane >> 5;
    const int t0 = blockIdx.x * 8 + wave * 2;
    const int t1 = t0 + 1;
    const bool v1 = (t1 < NTILES);
    if (t0 >= NTILES) return;   // no barriers below

    // A-fragments: lane holds C[32t+arow][k0*16 + khalf*8 .. +8] as bf16x8
    bf16x8 af0[4], af1[4];
#pragma unroll
    for (int k0 = 0; k0 < 4; ++k0) {
        {
            const float* p = cs + (size_t)(t0 * 32 + arow) * ND + k0 * 16 + khalf * 8;
            const float4 a0 = *(const float4*)p;
            const float4 a1 = *(const float4*)(p + 4);
            union { unsigned int u[4]; bf16x8 v; } t;
            t.u[0] = pack_bf16(a0.x, a0.y); t.u[1] = pack_bf16(a0.z, a0.w);
            t.u[2] = pack_bf16(a1.x, a1.y); t.u[3] = pack_bf16(a1.z, a1.w);
            af0[k0] = t.v;
        }
        if (v1) {
            const float* p = cs + (size_t)(t1 * 32 + arow) * ND + k0 * 16 + khalf * 8;
            const float4 a0 = *(const float4*)p;
            const float4 a1 = *(const float4*)(p + 4);
            union { unsigned int u[4]; bf16x8 v; } t;
            t.u[0] = pack_bf16(a0.x, a0.y); t.u[1] = pack_bf16(a0.z, a0.w);
            t.u[2] = pack_bf16(a1.x, a1.y); t.u[3] = pack_bf16(a1.z, a1.w);
            af1[k0] = t.v;
        }
    }

    for (int qt = 0; qt < 16; ++qt) {
        bf16x8 bf[4];
#pragma unroll
        for (int k0 = 0; k0 < 4; ++k0) {
            union { uint4 q; bf16x8 v; } t;
            t.q = *(const uint4*)(qlds + ((size_t)(qt * 4 + k0) * 64 + lane) * 4);
            bf[k0] = t.v;
        }
        const float tm = tlds[qt * 32 + (lane & 31)];
        const int query = qt * 32 + (lane & 31);

        f32x16 acc0;
#pragma unroll
        for (int i = 0; i < 16; ++i) acc0[i] = 0.f;
#pragma unroll
        for (int k0 = 0; k0 < 4; ++k0)
            acc0 = __builtin_amdgcn_mfma_f32_32x32x16_bf16(af0[k0], bf[k0], acc0, 0, 0, 0);
#pragma unroll
        for (int r = 0; r < 16; ++r) {
            const float s = acc0[r];
            if (s >= tm) {
                const int row = (r & 3) + 8 * (r >> 2) + 4 * khalf;
                const unsigned int p = atomicAdd(&cnt[query], 1u);
                if (p < CAP) buf[(size_t)query * CAP + p] = t0 * 32 + row;
            }
        }
        if (v1) {
            f32x16 acc1;
#pragma unroll
            for (int i = 0; i < 16; ++i) acc1[i] = 0.f;
#pragma unroll
            for (int k0 = 0; k0 < 4; ++k0)
                acc1 = __builtin_amdgcn_mfma_f32_32x32x16_bf16(af1[k0], bf[k0], acc1, 0, 0, 0);
#pragma unroll
            for (int r = 0; r < 16; ++r) {
                const float s = acc1[r];
                if (s >= tm) {
                    const int row = (r & 3) + 8 * (r >> 2) + 4 * khalf;
                    const unsigned int p = atomicAdd(&cnt[query], 1u);
                    if (p < CAP) buf[(size_t)query * CAP + p] = t1 * 32 + row;
                }
            }
        }
    }
}

// ---------------- K2: exact f32 rescore survivors + top-K ------------------
__device__ __forceinline__ bool prec(float av, int ai, float bv, int bi)
{
    return (av > bv) || (av == bv && ai < bi);
}

__device__ void bitonic_desc(float* v, int* ix, int n, int tid)
{
    for (int k = 2; k <= n; k <<= 1) {
        for (int j = k >> 1; j > 0; j >>= 1) {
            for (int i = tid; i < n; i += 256) {
                int p = i ^ j;
                if (p > i) {
                    bool swap_;
                    if ((i & k) == 0) swap_ = prec(v[p], ix[p], v[i], ix[i]);
                    else              swap_ = prec(v[i], ix[i], v[p], ix[p]);
                    if (swap_) {
                        float tv_ = v[i]; v[i] = v[p]; v[p] = tv_;
                        int   ti_ = ix[i]; ix[i] = ix[p]; ix[p] = ti_;
                    }
                }
            }
            __syncthreads();
        }
    }
}

__global__ __launch_bounds__(256) void k2_final(const float* __restrict__ qs,
                                                const float* __restrict__ cs,
                                                const unsigned int* __restrict__ cnt,
                                                const int* __restrict__ buf,
                                                float* __restrict__ out)
{
    __shared__ float sv[CAP];
    __shared__ int   si[CAP];
    __shared__ float tv[128];
    __shared__ int   ti[128];
    __shared__ float lq[ND];
    const int qi = blockIdx.x;
    const int tid = threadIdx.x;
    if (tid < ND) lq[tid] = qs[qi * ND + tid];
    __syncthreads();
    const unsigned int c = cnt[qi];
    const bool fix = (c < TOPK) || (c > CAP);
    if (!fix) {
        const int m = (int)c;
        int ns = 1024;
        while (ns < m) ns <<= 1;   // 1024 / 2048 / 4096
        for (int i = tid; i < ns; i += 256) {
            if (i < m) {
                const int n = buf[(size_t)qi * CAP + i];
                sv[i] = score_f32(cs + (size_t)n * ND, lq);
                si[i] = n;
            } else { sv[i] = -INFINITY; si[i] = 0x7fffffff; }
        }
        __syncthreads();
        bitonic_desc(sv, si, ns, tid);
        for (int j = tid; j < TOPK; j += 256) {
            out[qi * TOPK + j] = sv[j];
            out[NB * TOPK + qi * TOPK + j] = (float)si[j];
        }
    } else {
        // exact fallback (rare): chunked full scan with carried top-128
        for (int i = tid; i < 128; i += 256) { tv[i] = -INFINITY; ti[i] = 0x7fffffff; }
        __syncthreads();
        const int CH = CAP - 128;
        for (int base = 0; base < NC; base += CH) {
            for (int i = tid; i < CAP; i += 256) {
                if (i < 128) { sv[i] = tv[i]; si[i] = ti[i]; }
                else {
                    const int n = base + (i - 128);
                    if (n < NC) {
                        sv[i] = score_f32(cs + (size_t)n * ND, lq);
                        si[i] = n;
                    } else { sv[i] = -INFINITY; si[i] = 0x7fffffff; }
                }
            }
            __syncthreads();
            bitonic_desc(sv, si, CAP, tid);
            for (int i = tid; i < 128; i += 256) { tv[i] = sv[i]; ti[i] = si[i]; }
            __syncthreads();
        }
        for (int j = tid; j < TOPK; j += 256) {
            out[qi * TOPK + j] = tv[j];
            out[NB * TOPK + qi * TOPK + j] = (float)ti[j];
        }
    }
}

extern "C" void kernel_launch(void* const* d_in, const int* in_sizes, int n_in,
                              void* d_out, int out_size, void* d_ws, size_t ws_size,
                              hipStream_t stream)
{
    const float* qs = (const float*)d_in[0];
    const float* cs = (const float*)d_in[1];
    float*        T   = (float*)d_ws;
    unsigned int* cnt = (unsigned int*)((char*)d_ws + 2048);
    int*          buf = (int*)((char*)d_ws + 4096);
    float* out = (float*)d_out;

    hipMemsetAsync(cnt, 0, NB * sizeof(unsigned int), stream);
    k0_sample<<<NB, 256, 0, stream>>>(qs, cs, T);
    k1_mfma<<<(NTILES + 7) / 8, 256, 0, stream>>>(qs, cs, T, cnt, buf);
    k2_final<<<NB, 256, 0, stream>>>(qs, cs, cnt, buf, out);
}